// Round 1
// baseline (828.746 us; speedup 1.0000x reference)
//
#include <hip/hip_runtime.h>

#define TAU 5.0f
static constexpr int BSZ = 32768;
static constexpr int NB  = 8;
static constexpr int NW  = 256;
static constexpr int LW  = 64;
static constexpr int DF  = NB * LW;   // 512

// ---------------------------------------------------------------------------
// Quantization kernel: grid (BSZ/32, NB), block 512 (8 waves).
// Each block: book k, 32 batch rows. Each wave owns 4 rows end-to-end.
// Phase A: d[w] = ||x||^2 - 2 x.c_w + ||c_w||^2 ; softmax(-tau*d) over w.
//          (||x||^2 is constant over w -> dropped, softmax-invariant.)
// Phase B: z[l] = sum_w p[w] * c_w[l].
// f passthrough fused into the x staging load.
// LDS: cs 256x68 pad (69.6KB) + xs 8KB + ps 32KB + ccs 1KB  ~= 111KB -> 1 blk/CU.
// ---------------------------------------------------------------------------
__global__ __launch_bounds__(512, 2) void quant_kernel(
    const float* __restrict__ f, const float* __restrict__ cb,
    float* __restrict__ out_f, float* __restrict__ out_z, float* __restrict__ out_p)
{
    __shared__ __align__(16) float cs[NW * 68];     // codebook slice, pad 68
    __shared__ __align__(16) float ccs[NW];         // ||c_w||^2
    __shared__ __align__(16) float xs[32][LW];      // x tile
    __shared__ __align__(16) float ps[8][4][NW];    // per-wave p rows

    const int k    = blockIdx.y;
    const int r0   = blockIdx.x * 32;
    const int tid  = threadIdx.x;
    const int wid  = tid >> 6;
    const int lane = tid & 63;

    // stage codebook slice (coalesced 256B runs per word)
    for (int i = tid; i < NW * LW; i += 512) {
        int w = i >> 6, l = i & 63;
        cs[w * 68 + l] = cb[w * DF + k * LW + l];
    }
    // stage x tile + fused f passthrough
    for (int i = tid; i < 32 * LW; i += 512) {
        int r = i >> 6, l = i & 63;
        size_t gi = (size_t)(r0 + r) * DF + k * LW + l;
        float v = f[gi];
        xs[r][l] = v;
        out_f[gi] = v;
    }
    __syncthreads();
    if (tid < NW) {
        float s = 0.f;
        #pragma unroll
        for (int l4 = 0; l4 < 16; ++l4) {
            float4 c4 = *(const float4*)&cs[tid * 68 + l4 * 4];
            s += c4.x * c4.x + c4.y * c4.y + c4.z * c4.z + c4.w * c4.w;
        }
        ccs[tid] = s;
    }
    __syncthreads();
    // ---- no block barriers below: each wave's ps slice is private ----

    const int rb = wid * 4;            // this wave's 4 local rows

    // Phase A: distances. lane -> w in {lane, lane+64, lane+128, lane+192}
    float acc[4][4];                   // [w-group i][row r]
    #pragma unroll
    for (int i = 0; i < 4; ++i)
        #pragma unroll
        for (int r = 0; r < 4; ++r) acc[i][r] = 0.f;

    #pragma unroll 4
    for (int l4 = 0; l4 < 16; ++l4) {
        float4 c4[4];
        #pragma unroll
        for (int i = 0; i < 4; ++i)
            c4[i] = *(const float4*)&cs[(i * 64 + lane) * 68 + l4 * 4];
        #pragma unroll
        for (int r = 0; r < 4; ++r) {
            float4 x4 = *(const float4*)&xs[rb + r][l4 * 4];   // broadcast
            #pragma unroll
            for (int i = 0; i < 4; ++i)
                acc[i][r] += c4[i].x * x4.x + c4[i].y * x4.y
                           + c4[i].z * x4.z + c4[i].w * x4.w;
        }
    }

    float ccv[4];
    #pragma unroll
    for (int i = 0; i < 4; ++i) ccv[i] = ccs[i * 64 + lane];

    // softmax per row (wave-local butterfly) + p writeback
    #pragma unroll
    for (int r = 0; r < 4; ++r) {
        float li[4];
        #pragma unroll
        for (int i = 0; i < 4; ++i) li[i] = TAU * (2.f * acc[i][r] - ccv[i]);
        float m = fmaxf(fmaxf(li[0], li[1]), fmaxf(li[2], li[3]));
        #pragma unroll
        for (int off = 32; off >= 1; off >>= 1)
            m = fmaxf(m, __shfl_xor(m, off));
        float e[4], s = 0.f;
        #pragma unroll
        for (int i = 0; i < 4; ++i) { e[i] = __expf(li[i] - m); s += e[i]; }
        #pragma unroll
        for (int off = 32; off >= 1; off >>= 1)
            s += __shfl_xor(s, off);
        float inv = 1.f / s;
        size_t prow = (size_t)(r0 + rb + r) * (NB * NW) + (size_t)k * NW;
        #pragma unroll
        for (int i = 0; i < 4; ++i) {
            float p = e[i] * inv;
            ps[wid][r][i * 64 + lane] = p;
            out_p[prow + i * 64 + lane] = p;
        }
    }

    // Phase B: z = P @ C. lane -> l; c column reads conflict-free (pad 68).
    float z[4] = {0.f, 0.f, 0.f, 0.f};
    #pragma unroll 4
    for (int w = 0; w < NW; w += 4) {
        float c0 = cs[(w + 0) * 68 + lane];
        float c1 = cs[(w + 1) * 68 + lane];
        float c2 = cs[(w + 2) * 68 + lane];
        float c3 = cs[(w + 3) * 68 + lane];
        #pragma unroll
        for (int r = 0; r < 4; ++r) {
            float4 p4 = *(const float4*)&ps[wid][r][w];        // broadcast
            z[r] += p4.x * c0 + p4.y * c1 + p4.z * c2 + p4.w * c3;
        }
    }
    #pragma unroll
    for (int r = 0; r < 4; ++r)
        out_z[(size_t)(r0 + rb + r) * DF + (size_t)k * LW + lane] = z[r];
}

// ---------------------------------------------------------------------------
// MLP kernel: grid (BSZ*NB/32), block 256. 32 rows of f_split per block.
// h = relu(x @ W1 + b1)  (W1 column per thread in 64 VGPRs, x broadcast LDS)
// logits = log_softmax(h @ W2 + b2)  (thread = (row, class), W2 transposed LDS)
// LDS ~50KB -> 3 blk/CU.
// ---------------------------------------------------------------------------
__global__ __launch_bounds__(256, 3) void mlp_kernel(
    const float* __restrict__ f, const float* __restrict__ W1,
    const float* __restrict__ b1, const float* __restrict__ W2,
    const float* __restrict__ b2, float* __restrict__ out_lg)
{
    __shared__ __align__(16) float xs[32][LW];      // 8KB
    __shared__ __align__(16) float hs[32 * 260];    // 33.3KB, pad 260
    __shared__ __align__(16) float w2t[8 * 260];    // 8.3KB, transposed W2

    const int tid = threadIdx.x;
    const int m0  = blockIdx.x * 32;

    // W1 column tid -> registers (coalesced, L2-resident after first blocks)
    float w1r[64];
    #pragma unroll
    for (int l = 0; l < 64; ++l) w1r[l] = W1[l * 256 + tid];
    const float b1r = b1[tid];

    for (int i = tid; i < 32 * LW; i += 256)
        ((float*)xs)[i] = f[(size_t)m0 * LW + i];
    for (int i = tid; i < 8 * NW; i += 256) {
        int c = i >> 8, j = i & 255;
        w2t[c * 260 + j] = W2[j * 8 + c];
    }
    __syncthreads();

    // Phase 1: h[r][tid], 2 rows at a time for FMA ILP
    for (int r = 0; r < 32; r += 2) {
        float a0 = b1r, a1 = b1r;
        #pragma unroll
        for (int l4 = 0; l4 < 16; ++l4) {
            float4 x0 = *(const float4*)&xs[r][l4 * 4];        // broadcast
            float4 x1 = *(const float4*)&xs[r + 1][l4 * 4];
            a0 += x0.x * w1r[l4*4+0] + x0.y * w1r[l4*4+1]
                + x0.z * w1r[l4*4+2] + x0.w * w1r[l4*4+3];
            a1 += x1.x * w1r[l4*4+0] + x1.y * w1r[l4*4+1]
                + x1.z * w1r[l4*4+2] + x1.w * w1r[l4*4+3];
        }
        hs[(r + 0) * 260 + tid] = fmaxf(a0, 0.f);
        hs[(r + 1) * 260 + tid] = fmaxf(a1, 0.f);
    }
    __syncthreads();

    // Phase 2: thread = (row r, class c); dot over 256 hidden units
    const int r = tid >> 3, c = tid & 7;
    float s = b2[c];
    #pragma unroll 8
    for (int j4 = 0; j4 < 64; ++j4) {
        float4 h4 = *(const float4*)&hs[r * 260 + j4 * 4];
        float4 w4 = *(const float4*)&w2t[c * 260 + j4 * 4];
        s += h4.x * w4.x + h4.y * w4.y + h4.z * w4.z + h4.w * w4.w;
    }
    // log_softmax over the 8 classes (8-lane groups)
    float m = s;
    m = fmaxf(m, __shfl_xor(m, 1));
    m = fmaxf(m, __shfl_xor(m, 2));
    m = fmaxf(m, __shfl_xor(m, 4));
    float e = __expf(s - m);
    float se = e;
    se += __shfl_xor(se, 1);
    se += __shfl_xor(se, 2);
    se += __shfl_xor(se, 4);
    float lse = m + __logf(se);
    out_lg[(size_t)(m0 + r) * 8 + c] = s - lse;
}

extern "C" void kernel_launch(void* const* d_in, const int* in_sizes, int n_in,
                              void* d_out, int out_size, void* d_ws, size_t ws_size,
                              hipStream_t stream) {
    const float* f  = (const float*)d_in[0];
    const float* cb = (const float*)d_in[1];
    const float* W1 = (const float*)d_in[2];
    const float* b1 = (const float*)d_in[3];
    const float* W2 = (const float*)d_in[4];
    const float* b2 = (const float*)d_in[5];

    float* out    = (float*)d_out;
    float* out_f  = out;
    float* out_z  = out_f + (size_t)BSZ * DF;
    float* out_p  = out_z + (size_t)BSZ * DF;
    float* out_lg = out_p + (size_t)BSZ * NB * NW;

    hipLaunchKernelGGL(quant_kernel, dim3(BSZ / 32, NB), dim3(512), 0, stream,
                       f, cb, out_f, out_z, out_p);
    hipLaunchKernelGGL(mlp_kernel, dim3(BSZ * NB / 32), dim3(256), 0, stream,
                       f, W1, b1, W2, b2, out_lg);
}

// Round 3
// 188.610 us; speedup vs baseline: 4.3940x; 4.3940x over previous
//
#include <hip/hip_runtime.h>

typedef __fp16   pk16x2 __attribute__((ext_vector_type(2)));
typedef _Float16 f16x4 __attribute__((ext_vector_type(4)));
typedef _Float16 f16x8 __attribute__((ext_vector_type(8)));
typedef float    f32x16 __attribute__((ext_vector_type(16)));

static constexpr int BSZ = 32768;
static constexpr int NB  = 8;
static constexpr int NW  = 256;
static constexpr int LW  = 64;
static constexpr int DF  = 512;
#define TAU   5.0f
#define LOG2E 1.44269504088896f
#define LN2   0.69314718055994f

union U2 { pk16x2 h; unsigned u; };
union U8 { f16x8 v; unsigned u[4]; };
union U4 { f16x4 v; unsigned u[2]; };
union F4 { float4 v; float a[4]; };

__device__ inline unsigned pku(float a, float b) {
    U2 c; c.h = __builtin_amdgcn_cvt_pkrtz(a, b); return c.u;
}
__device__ inline pk16x2 pkh(float a, float b) {
    return __builtin_amdgcn_cvt_pkrtz(a, b);
}

// ---------------------------------------------------------------------------
// Quant kernel: grid (BSZ/128, NB), block 256 (4 waves). Book k per block.
// Wave w owns 32 rows. Swapped dist GEMM: A=codebook(32w x 16l), B=x^T ->
// D[w][r]: col r = lane&31, w offsets in regs. Softmax in-register
// (1 shfl_xor(32)). z GEMM: A=P (in-reg frags via lane32 exchange + pkrtz),
// B=ctt. x split hi/lo fp16 for accuracy; c single fp16.
// LDS: ct 32K + ctt 32K + ccs 1K = 65 KB -> 2 blocks/CU.
// ---------------------------------------------------------------------------
__global__ __launch_bounds__(256, 2) void quant_kernel(
    const float* __restrict__ f, const float* __restrict__ cb,
    float* __restrict__ out_z, float* __restrict__ out_p)
{
    __shared__ _Float16 ct [NW * LW];   // [w][l], 16B chunk c=l>>3 stored at c^(w&7)
    __shared__ _Float16 ctt[LW * NW];   // [l][w], chunk c=w>>3 stored at c^(l&7) (low 3 bits)
    __shared__ float    ccs[NW];        // ||c_w||^2 (fp32)

    const int k    = blockIdx.y;
    const int r0   = blockIdx.x * 128;
    const int tid  = threadIdx.x;
    const int wid  = tid >> 6;
    const int lane = tid & 63;
    const int lr   = lane & 31;
    const int hi   = lane >> 5;
    const int row  = r0 + wid * 32 + lr;      // this lane's batch row

    // ---- x fragment loads: x_[ks*8+j] = f[row][k*64 + ks*16 + hi*8 + j] ----
    float x_[32];
    {
        const float* fr = f + (size_t)row * DF + k * LW + hi * 8;
        #pragma unroll
        for (int i = 0; i < 8; ++i)
            *(float4*)&x_[i * 4] = *(const float4*)(fr + (i >> 1) * 16 + (i & 1) * 4);
    }

    // ---- codebook staging: thread t owns word w=t ----
    {
        const float* cw = cb + (size_t)tid * DF + k * LW;
        float c_[64];
        #pragma unroll
        for (int i = 0; i < 16; ++i)
            *(float4*)&c_[i * 4] = *(const float4*)(cw + i * 4);
        float cc = 0.f;
        #pragma unroll
        for (int l = 0; l < 64; ++l) cc += c_[l] * c_[l];
        ccs[tid] = cc;
        #pragma unroll
        for (int c8 = 0; c8 < 8; ++c8) {
            U8 u;
            #pragma unroll
            for (int m = 0; m < 4; ++m)
                u.u[m] = pku(c_[c8 * 8 + 2 * m], c_[c8 * 8 + 2 * m + 1]);
            *(f16x8*)&ct[tid * 64 + (c8 ^ (tid & 7)) * 8] = u.v;
            #pragma unroll
            for (int j = 0; j < 8; ++j) {
                int l = c8 * 8 + j;
                ctt[l * 256 + (((tid >> 3) ^ (l & 7))) * 8 + (tid & 7)] = (_Float16)c_[l];
            }
        }
    }

    // ---- x -> fp16 hi/lo split fragments ----
    f16x8 bxh[4], bxl[4];
    #pragma unroll
    for (int ks = 0; ks < 4; ++ks) {
        U8 uh, ul;
        #pragma unroll
        for (int m = 0; m < 4; ++m) {
            float a = x_[ks * 8 + 2 * m], b = x_[ks * 8 + 2 * m + 1];
            pk16x2 ph = pkh(a, b);
            U2 c; c.h = ph;
            uh.u[m] = c.u;
            ul.u[m] = pku(a - (float)ph[0], b - (float)ph[1]);
        }
        bxh[ks] = uh.v; bxl[ks] = ul.v;
    }

    __syncthreads();

    // ---- distance MFMAs: acc[wt][q] = dot(c_w, x_row) ----
    f32x16 acc[8];
    #pragma unroll
    for (int wt = 0; wt < 8; ++wt) acc[wt] = {};
    #pragma unroll
    for (int wt = 0; wt < 8; ++wt) {
        const int w = wt * 32 + lr;
        #pragma unroll
        for (int ks = 0; ks < 4; ++ks) {
            f16x8 a = *(const f16x8*)&ct[w * 64 + (((ks * 2 + hi) ^ (lr & 7))) * 8];
            acc[wt] = __builtin_amdgcn_mfma_f32_32x32x16_f16(a, bxh[ks], acc[wt], 0, 0, 0);
            acc[wt] = __builtin_amdgcn_mfma_f32_32x32x16_f16(a, bxl[ks], acc[wt], 0, 0, 0);
        }
    }

    // ---- softmax over all 256 w (exp2 domain); logit = (2*dot - cc)*TAU ----
    const float KK = TAU * LOG2E;
    float mx = -1e30f;
    #pragma unroll
    for (int wt = 0; wt < 8; ++wt) {
        #pragma unroll
        for (int g = 0; g < 4; ++g) {
            F4 cc4; cc4.v = *(const float4*)&ccs[wt * 32 + g * 8 + hi * 4];
            #pragma unroll
            for (int j = 0; j < 4; ++j) {
                int q = g * 4 + j;
                float li = (2.f * acc[wt][q] - cc4.a[j]) * KK;
                acc[wt][q] = li;
                mx = fmaxf(mx, li);
            }
        }
    }
    mx = fmaxf(mx, __shfl_xor(mx, 32));
    float s = 0.f;
    #pragma unroll
    for (int wt = 0; wt < 8; ++wt) {
        #pragma unroll
        for (int q = 0; q < 16; ++q) {
            float e = __builtin_amdgcn_exp2f(acc[wt][q] - mx);
            acc[wt][q] = e; s += e;
        }
    }
    s += __shfl_xor(s, 32);
    const float inv = 1.f / s;
    #pragma unroll
    for (int wt = 0; wt < 8; ++wt) {
        #pragma unroll
        for (int q = 0; q < 16; ++q) acc[wt][q] *= inv;
    }

    // ---- z GEMM + p writeback. For frag ks, lane needs p at w=ks*16+hi*8+j.
    // Value for offset o=(q&3)+8*(q>>2)+4*hi' lives at reg q, half hi'.
    float* prow = out_p + (size_t)row * (NB * NW) + (size_t)k * NW + hi * 8;
    f32x16 zacc[2];
    zacc[0] = {}; zacc[1] = {};
    #pragma unroll
    for (int ks = 0; ks < 16; ++ks) {
        const int wt = ks >> 1;
        const int q0 = (ks & 1) * 8;
        float v[8];
        #pragma unroll
        for (int i = 0; i < 4; ++i) {
            float a0 = acc[wt][q0 + i];
            float a1 = acc[wt][q0 + 4 + i];
            float snd = hi ? a0 : a1;
            float rcv = __shfl_xor(snd, 32);
            v[i]     = hi ? rcv : a0;
            v[4 + i] = hi ? a1 : rcv;
        }
        *(float4*)(prow + ks * 16)     = float4{v[0], v[1], v[2], v[3]};
        *(float4*)(prow + ks * 16 + 4) = float4{v[4], v[5], v[6], v[7]};
        U8 pa;
        pa.u[0] = pku(v[0], v[1]); pa.u[1] = pku(v[2], v[3]);
        pa.u[2] = pku(v[4], v[5]); pa.u[3] = pku(v[6], v[7]);
        #pragma unroll
        for (int nt = 0; nt < 2; ++nt) {
            const int l = nt * 32 + lr;
            f16x8 bz = *(const f16x8*)&ctt[l * 256 + (((ks * 2 + hi) ^ (lr & 7))) * 8];
            zacc[nt] = __builtin_amdgcn_mfma_f32_32x32x16_f16(pa.v, bz, zacc[nt], 0, 0, 0);
        }
    }

    // ---- z store: D rows = batch-row offsets, cols = l ----
    #pragma unroll
    for (int nt = 0; nt < 2; ++nt) {
        #pragma unroll
        for (int q = 0; q < 16; ++q) {
            int rr = (q & 3) + 8 * (q >> 2) + 4 * hi;
            out_z[(size_t)(r0 + wid * 32 + rr) * DF + k * LW + nt * 32 + lr] = zacc[nt][q];
        }
    }
}

// ---------------------------------------------------------------------------
// MLP kernel: grid (BSZ*NB/128), block 256 (4 waves). 128 f_split rows/block.
// G1 swapped: A=W1^T (256 hcols), B=x^T -> h in regs (col r = lane&31).
// G2: A=W2^T (8 valid rows of 32), B=h^T via lane32 exchange. out_f fused.
// LDS: w1t 32K + xs 16K + w2t 4K + b1s 1K = 53 KB.
// ---------------------------------------------------------------------------
__global__ __launch_bounds__(256, 2) void mlp_kernel(
    const float* __restrict__ f, const float* __restrict__ W1,
    const float* __restrict__ b1, const float* __restrict__ W2,
    const float* __restrict__ b2, float* __restrict__ out_f,
    float* __restrict__ out_lg)
{
    __shared__ _Float16 w1t[NW * LW];     // [hcol][l], chunk swizzle ^(hcol&7)
    __shared__ _Float16 xs [128 * LW];    // [r][l],  chunk swizzle ^(r&7)
    __shared__ _Float16 w2t[8 * NW];      // [class][hcol], chunk swizzle ^class
    __shared__ float    b1s[NW];
    __shared__ float    b2s[8];

    const int tid  = threadIdx.x;
    const int wid  = tid >> 6;
    const int lane = tid & 63;
    const int lr   = lane & 31;
    const int hi   = lane >> 5;
    const size_t m0 = (size_t)blockIdx.x * 128;

    // ---- stage x tile (+ fused out_f passthrough) ----
    #pragma unroll
    for (int i = 0; i < 8; ++i) {
        int c = i * 256 + tid;            // float4 chunk id, 2048 total
        int r = c >> 4, l4 = c & 15;
        float4 v = *(const float4*)(f + m0 * LW + (size_t)c * 4);
        *(float4*)(out_f + m0 * LW + (size_t)c * 4) = v;
        U4 w; w.u[0] = pku(v.x, v.y); w.u[1] = pku(v.z, v.w);
        *(f16x4*)&xs[r * 64 + (((l4 >> 1) ^ (r & 7))) * 8 + (l4 & 1) * 4] = w.v;
    }
    // ---- stage W1^T: thread t owns hcol t ----
    {
        float wv[64];
        #pragma unroll
        for (int l = 0; l < 64; ++l) wv[l] = W1[l * 256 + tid];
        #pragma unroll
        for (int c8 = 0; c8 < 8; ++c8) {
            U8 u;
            #pragma unroll
            for (int m = 0; m < 4; ++m)
                u.u[m] = pku(wv[c8 * 8 + 2 * m], wv[c8 * 8 + 2 * m + 1]);
            *(f16x8*)&w1t[tid * 64 + (c8 ^ (tid & 7)) * 8] = u.v;
        }
    }
    // ---- stage W2^T [8][256]: thread t -> class t>>5, chunk t&31 ----
    {
        int m = tid >> 5, c = tid & 31;
        U8 u;
        #pragma unroll
        for (int mm = 0; mm < 4; ++mm)
            u.u[mm] = pku(W2[(c * 8 + 2 * mm) * 8 + m], W2[(c * 8 + 2 * mm + 1) * 8 + m]);
        *(f16x8*)&w2t[m * 256 + (c ^ m) * 8] = u.v;
    }
    b1s[tid] = b1[tid];
    if (tid < 8) b2s[tid] = b2[tid];
    __syncthreads();

    // ---- G1: h = relu(x @ W1 + b1), swapped ----
    f16x8 bx[4];
    #pragma unroll
    for (int ks = 0; ks < 4; ++ks)
        bx[ks] = *(const f16x8*)&xs[(wid * 32 + lr) * 64 + (((ks * 2 + hi) ^ (lr & 7))) * 8];

    f32x16 acc1[8];
    #pragma unroll
    for (int ht = 0; ht < 8; ++ht) acc1[ht] = {};
    #pragma unroll
    for (int ht = 0; ht < 8; ++ht) {
        const int h = ht * 32 + lr;
        #pragma unroll
        for (int ks = 0; ks < 4; ++ks) {
            f16x8 a = *(const f16x8*)&w1t[h * 64 + (((ks * 2 + hi) ^ (lr & 7))) * 8];
            acc1[ht] = __builtin_amdgcn_mfma_f32_32x32x16_f16(a, bx[ks], acc1[ht], 0, 0, 0);
        }
    }
    #pragma unroll
    for (int ht = 0; ht < 8; ++ht) {
        #pragma unroll
        for (int g = 0; g < 4; ++g) {
            F4 b4; b4.v = *(const float4*)&b1s[ht * 32 + g * 8 + hi * 4];
            #pragma unroll
            for (int j = 0; j < 4; ++j) {
                int q = g * 4 + j;
                acc1[ht][q] = fmaxf(acc1[ht][q] + b4.a[j], 0.f);
            }
        }
    }

    // ---- G2: logits = h @ W2 + b2 (A = W2^T padded to 32 rows) ----
    f32x16 acc2 = {};
    #pragma unroll
    for (int ks = 0; ks < 16; ++ks) {
        const int ht = ks >> 1;
        const int q0 = (ks & 1) * 8;
        float v[8];
        #pragma unroll
        for (int i = 0; i < 4; ++i) {
            float a0 = acc1[ht][q0 + i];
            float a1 = acc1[ht][q0 + 4 + i];
            float snd = hi ? a0 : a1;
            float rcv = __shfl_xor(snd, 32);
            v[i]     = hi ? rcv : a0;
            v[4 + i] = hi ? a1 : rcv;
        }
        U8 hb;
        hb.u[0] = pku(v[0], v[1]); hb.u[1] = pku(v[2], v[3]);
        hb.u[2] = pku(v[4], v[5]); hb.u[3] = pku(v[6], v[7]);
        f16x8 aw2 = *(const f16x8*)&w2t[(lr & 7) * 256 + (((ks * 2 + hi) ^ (lr & 7))) * 8];
        acc2 = __builtin_amdgcn_mfma_f32_32x32x16_f16(aw2, hb.v, acc2, 0, 0, 0);
    }

    // ---- log_softmax over 8 classes: regs q=0..3 hold classes q+4*hi ----
    F4 b2v; b2v.v = *(const float4*)&b2s[hi * 4];
    float lg[4];
    #pragma unroll
    for (int q = 0; q < 4; ++q) lg[q] = acc2[q] + b2v.a[q];
    float m = fmaxf(fmaxf(lg[0], lg[1]), fmaxf(lg[2], lg[3]));
    m = fmaxf(m, __shfl_xor(m, 32));
    float se = 0.f;
    #pragma unroll
    for (int q = 0; q < 4; ++q) se += __builtin_amdgcn_exp2f((lg[q] - m) * LOG2E);
    se += __shfl_xor(se, 32);
    float lse = m + __builtin_amdgcn_logf(se) * LN2;
    float4 o = float4{lg[0] - lse, lg[1] - lse, lg[2] - lse, lg[3] - lse};
    *(float4*)(out_lg + (m0 + wid * 32 + lr) * 8 + hi * 4) = o;
}

extern "C" void kernel_launch(void* const* d_in, const int* in_sizes, int n_in,
                              void* d_out, int out_size, void* d_ws, size_t ws_size,
                              hipStream_t stream) {
    const float* f  = (const float*)d_in[0];
    const float* cb = (const float*)d_in[1];
    const float* W1 = (const float*)d_in[2];
    const float* b1 = (const float*)d_in[3];
    const float* W2 = (const float*)d_in[4];
    const float* b2 = (const float*)d_in[5];

    float* out    = (float*)d_out;
    float* out_f  = out;
    float* out_z  = out_f + (size_t)BSZ * DF;
    float* out_p  = out_z + (size_t)BSZ * DF;
    float* out_lg = out_p + (size_t)BSZ * NB * NW;

    hipLaunchKernelGGL(quant_kernel, dim3(BSZ / 128, NB), dim3(256), 0, stream,
                       f, cb, out_z, out_p);
    hipLaunchKernelGGL(mlp_kernel, dim3(BSZ * NB / 128), dim3(256), 0, stream,
                       f, W1, b1, W2, b2, out_f, out_lg);
}